// Round 2
// baseline (109.242 us; speedup 1.0000x reference)
//
#include <hip/hip_runtime.h>
#include <hip/hip_bf16.h>

#define BB 4
#define NN 512
#define FD 256
#define FI 128

// workspace layout (float offsets)
#define OFF_AIN   0          // 2048*128  A_in' (bias folded)
#define OFF_D     262144     // 2048*128  D = -(A_out + bias_out)
#define OFF_UIN   524288     // 128*256   We1@Wi
#define OFF_UOUT  557056     // 128*256   We1@Wo
#define OFF_WC0   589824     // 128       (We1@Wp)[:,0]
#define OFF_WC1   589952     // 128       (We1@Wp)[:,1]
#define OFF_BIN   590080     // 128       We1@(bi+bp)+be1
#define OFF_BOUT  590208     // 128       We1@bo
#define OFF_PART  590336     // 4*128*512 partial maxes
// total 852480 floats = 3.25 MB

__device__ __forceinline__ float fast_gelu(float x) {
    // gelu(x) ~= x * sigmoid(1.5957691216*(x + 0.044715 x^3))
    float x2 = x * x;
    float s  = __fmaf_rn(0.071354814f, x2, 1.5957691216f);
    float zs = x * s;
    float e  = __expf(zs);
    float r  = __builtin_amdgcn_rcpf(e + 1.0f);
    return __fmaf_rn(-x, r, x);   // x*(1 - 1/(1+e^zs)) = x*sigmoid(zs)
}

// ---- kernel 1: fold weights -------------------------------------------------
__global__ __launch_bounds__(256) void prep_kernel(
    const float* __restrict__ Wp, const float* __restrict__ bp,
    const float* __restrict__ Wi, const float* __restrict__ bi,
    const float* __restrict__ Wo, const float* __restrict__ bo,
    const float* __restrict__ We1, const float* __restrict__ be1,
    float* ws)
{
    int t = blockIdx.x * 256 + threadIdx.x;   // 0..32767
    int g = t >> 8, d = t & 255;
    const float* wrow = We1 + g * FI;
    float accI = 0.f, accO = 0.f;
    for (int f = 0; f < FI; ++f) {
        float w = wrow[f];
        accI = __fmaf_rn(w, Wi[f * FD + d], accI);
        accO = __fmaf_rn(w, Wo[f * FD + d], accO);
    }
    ws[OFF_UIN  + t] = accI;
    ws[OFF_UOUT + t] = accO;
    if (blockIdx.x == 0 && t < FI) {
        const float* wr = We1 + t * FI;
        float a0 = 0.f, a1 = 0.f, abi = 0.f, abo = 0.f;
        for (int f = 0; f < FI; ++f) {
            float w = wr[f];
            a0  = __fmaf_rn(w, Wp[f * 2 + 0], a0);
            a1  = __fmaf_rn(w, Wp[f * 2 + 1], a1);
            abi = __fmaf_rn(w, bi[f] + bp[f], abi);
            abo = __fmaf_rn(w, bo[f], abo);
        }
        ws[OFF_WC0  + t] = a0;
        ws[OFF_WC1  + t] = a1;
        ws[OFF_BIN  + t] = abi + be1[t];
        ws[OFF_BOUT + t] = abo;
    }
}

// ---- kernel 2: per-node projections A_in', D --------------------------------
__global__ __launch_bounds__(256) void node_proj_kernel(
    const float* __restrict__ x, float* ws)
{
    __shared__ __align__(16) float xs[8][FD];
    int nb = blockIdx.x * 8;                       // 256 blocks * 8 nodes
    for (int s = threadIdx.x; s < 8 * FD; s += 256)
        xs[s >> 8][s & 255] = x[nb * FD + s];
    __syncthreads();
    int t = threadIdx.x;
    int g = t & 127;
    bool isIn = (t < 128);
    const float* U = ws + (isIn ? OFF_UIN : OFF_UOUT) + g * FD;
    float bias = ws[(isIn ? OFF_BIN : OFF_BOUT) + g];
    float acc[8] = {0.f,0.f,0.f,0.f,0.f,0.f,0.f,0.f};
    for (int d4 = 0; d4 < FD / 4; ++d4) {
        float4 u = ((const float4*)U)[d4];
        #pragma unroll
        for (int k = 0; k < 8; ++k) {
            float4 xv = ((const float4*)&xs[k][0])[d4];
            acc[k] = __fmaf_rn(u.x, xv.x, acc[k]);
            acc[k] = __fmaf_rn(u.y, xv.y, acc[k]);
            acc[k] = __fmaf_rn(u.z, xv.z, acc[k]);
            acc[k] = __fmaf_rn(u.w, xv.w, acc[k]);
        }
    }
    #pragma unroll
    for (int k = 0; k < 8; ++k) {
        int n = nb + k;
        if (isIn) ws[OFF_AIN + n * FI + g] = acc[k] + bias;
        else      ws[OFF_D   + n * FI + g] = -(acc[k] + bias);
    }
}

// ---- kernel 3: fused edge MLP + supress + partial max over i ----------------
#define I_PER_BLOCK 16
#define I_PER_WAVE  4

__global__ __launch_bounds__(256) void edge_kernel(
    const float* __restrict__ pos, const float* __restrict__ sup,
    const float* __restrict__ We2, const float* __restrict__ be2p,
    float* ws)
{
    __shared__ __align__(16) float sD[64 * 130];       // padded rows
    __shared__ __align__(16) float sA[I_PER_BLOCK * FI];
    __shared__ __align__(16) float sw0[FI], sw1[FI], sv[FI];

    int bid = blockIdx.x;            // 1024 = 4b * 8jt * 32ig
    int b   = bid >> 8;
    int jt  = (bid >> 5) & 7;
    int ig  = bid & 31;
    int tid = threadIdx.x;
    int w = tid >> 6, lane = tid & 63;
    int j = jt * 64 + lane;
    int ibase = ig * I_PER_BLOCK + w * I_PER_WAVE;

    const float* Ain = ws + OFF_AIN + (b * NN + ig * I_PER_BLOCK) * FI;
    const float* Dg  = ws + OFF_D   + (b * NN + jt * 64) * FI;
    for (int s = tid; s < I_PER_BLOCK * FI; s += 256) sA[s] = Ain[s];
    for (int s = tid; s < 64 * FI; s += 256) {
        int r = s >> 7, c = s & 127;
        sD[r * 130 + c] = Dg[s];
    }
    if (tid < FI) {
        sw0[tid] = ws[OFF_WC0 + tid];
        sw1[tid] = ws[OFF_WC1 + tid];
        sv[tid]  = We2[tid];
    }
    __syncthreads();

    const float2* pos2 = (const float2*)pos;
    float p0[I_PER_WAVE], p1[I_PER_WAVE];
    #pragma unroll
    for (int ii = 0; ii < I_PER_WAVE; ++ii) {
        float2 pp = pos2[(size_t)(b * NN + ibase + ii) * NN + j];
        p0[ii] = pp.x; p1[ii] = pp.y;
    }
    float z[I_PER_WAVE] = {0.f, 0.f, 0.f, 0.f};
    const float2* sDp = (const float2*)sD + lane * 65;

    for (int gq = 0; gq < FI / 4; ++gq) {
        float2 d01 = sDp[gq * 2];
        float2 d23 = sDp[gq * 2 + 1];
        float4 w0 = ((const float4*)sw0)[gq];
        float4 w1 = ((const float4*)sw1)[gq];
        float4 vv = ((const float4*)sv)[gq];
        #pragma unroll
        for (int ii = 0; ii < I_PER_WAVE; ++ii) {
            float4 a = ((const float4*)sA)[(w * I_PER_WAVE + ii) * (FI / 4) + gq];
            float y0 = __fmaf_rn(w1.x, p1[ii], __fmaf_rn(w0.x, p0[ii], a.x + d01.x));
            float y1 = __fmaf_rn(w1.y, p1[ii], __fmaf_rn(w0.y, p0[ii], a.y + d01.y));
            float y2 = __fmaf_rn(w1.z, p1[ii], __fmaf_rn(w0.z, p0[ii], a.z + d23.x));
            float y3 = __fmaf_rn(w1.w, p1[ii], __fmaf_rn(w0.w, p0[ii], a.w + d23.y));
            z[ii] = __fmaf_rn(vv.x, fast_gelu(y0), z[ii]);
            z[ii] = __fmaf_rn(vv.y, fast_gelu(y1), z[ii]);
            z[ii] = __fmaf_rn(vv.z, fast_gelu(y2), z[ii]);
            z[ii] = __fmaf_rn(vv.w, fast_gelu(y3), z[ii]);
        }
    }

    float be2 = *be2p;
    float m = -INFINITY;
    #pragma unroll
    for (int ii = 0; ii < I_PER_WAVE; ++ii) {
        float sEl = (z[ii] + be2) * sup[(size_t)(b * NN + ibase + ii) * NN + j];
        m = fmaxf(m, sEl);
    }
    int c = ig * 4 + w;                       // 0..127, unique per i-chunk
    ws[OFF_PART + (b * 128 + c) * NN + j] = m;
}

// ---- kernel 4: reduce partials + node FFN -----------------------------------
__global__ __launch_bounds__(256) void final_kernel(
    const float* __restrict__ Wn1, const float* __restrict__ bn1,
    const float* __restrict__ Wn2, const float* __restrict__ bn2,
    const float* ws, float* __restrict__ out)
{
    __shared__ __align__(16) float red[16][17];
    __shared__ float nm[16];
    __shared__ __align__(16) float h1[16][FD];
    int nb = blockIdx.x * 16;                 // 128 blocks * 16 nodes
    int b  = nb >> 9;
    int j0 = nb & 511;
    int t = threadIdx.x;
    int k = t & 15, cc = t >> 4;
    const float* P = ws + OFF_PART + (size_t)b * 128 * NN;
    float m = -INFINITY;
    #pragma unroll
    for (int mm = 0; mm < 8; ++mm) {
        int c = cc + 16 * mm;
        m = fmaxf(m, P[c * NN + j0 + k]);
    }
    red[k][cc] = m;
    __syncthreads();
    if (t < 16) {
        float m2 = red[t][0];
        #pragma unroll
        for (int q = 1; q < 16; ++q) m2 = fmaxf(m2, red[t][q]);
        nm[t] = m2;
    }
    __syncthreads();
    // h1 = relu(nm * Wn1 + bn1)
    {
        float wv = Wn1[t];        // Wn1 shape [256,1]
        float bv = bn1[t];
        #pragma unroll
        for (int kk = 0; kk < 16; ++kk)
            h1[kk][t] = fmaxf(0.f, __fmaf_rn(nm[kk], wv, bv));
    }
    __syncthreads();
    // h2 = relu(h1 @ Wn2^T + bn2), thread t = output feature e
    float acc[16];
    #pragma unroll
    for (int kk = 0; kk < 16; ++kk) acc[kk] = 0.f;
    const float4* w2 = (const float4*)(Wn2 + t * FD);
    for (int d4 = 0; d4 < FD / 4; ++d4) {
        float4 wv = w2[d4];
        #pragma unroll
        for (int kk = 0; kk < 16; ++kk) {
            float4 xv = ((const float4*)&h1[kk][0])[d4];
            acc[kk] = __fmaf_rn(wv.x, xv.x, acc[kk]);
            acc[kk] = __fmaf_rn(wv.y, xv.y, acc[kk]);
            acc[kk] = __fmaf_rn(wv.z, xv.z, acc[kk]);
            acc[kk] = __fmaf_rn(wv.w, xv.w, acc[kk]);
        }
    }
    float bb = bn2[t];
    #pragma unroll
    for (int kk = 0; kk < 16; ++kk)
        out[(size_t)(nb + kk) * FD + t] = fmaxf(0.f, acc[kk] + bb);
}

extern "C" void kernel_launch(void* const* d_in, const int* in_sizes, int n_in,
                              void* d_out, int out_size, void* d_ws, size_t ws_size,
                              hipStream_t stream) {
    (void)in_sizes; (void)n_in; (void)out_size; (void)ws_size;
    const float* node = (const float*)d_in[0];
    const float* sup  = (const float*)d_in[1];
    const float* pos  = (const float*)d_in[2];
    const float* Wp   = (const float*)d_in[3];
    const float* bp   = (const float*)d_in[4];
    const float* Wi   = (const float*)d_in[5];
    const float* bi   = (const float*)d_in[6];
    const float* Wo   = (const float*)d_in[7];
    const float* bo   = (const float*)d_in[8];
    const float* We1  = (const float*)d_in[9];
    const float* be1  = (const float*)d_in[10];
    const float* We2  = (const float*)d_in[11];
    const float* be2  = (const float*)d_in[12];
    const float* Wn1  = (const float*)d_in[13];
    const float* bn1  = (const float*)d_in[14];
    const float* Wn2  = (const float*)d_in[15];
    const float* bn2  = (const float*)d_in[16];
    float* ws  = (float*)d_ws;
    float* out = (float*)d_out;

    prep_kernel<<<128, 256, 0, stream>>>(Wp, bp, Wi, bi, Wo, bo, We1, be1, ws);
    node_proj_kernel<<<256, 256, 0, stream>>>(node, ws);
    edge_kernel<<<1024, 256, 0, stream>>>(pos, sup, We2, be2, ws);
    final_kernel<<<128, 256, 0, stream>>>(Wn1, bn1, Wn2, bn2, ws, out);
}

// Round 4
// 104.550 us; speedup vs baseline: 1.0449x; 1.0449x over previous
//
#include <hip/hip_runtime.h>
#include <hip/hip_bf16.h>

#define BB 4
#define NN 512
#define FD 256
#define FI 128

// workspace layout (float offsets)
#define OFF_AIN   0          // 2048*128  A_in' (bias folded)
#define OFF_D     262144     // 2048*128  D = -(A_out + bias_out)
#define OFF_UINT  524288     // 256*128   (We1@Wi) transposed [d][g]
#define OFF_UOUTT 557056     // 256*128   (We1@Wo) transposed [d][g]
#define OFF_COEF  589824     // 32*16     per-gq packed {w0[4], w1[4], v[4], pad[4]}
#define OFF_BIN   590336     // 128       We1@(bi+bp)+be1
#define OFF_BOUT  590464     // 128       We1@bo
#define OFF_PART  590592     // 4*128*512 partial maxes
// total 852736 floats = 3.25 MB

// gelu(x) ~= x * sigmoid(1.5957691216*(x + 0.044715 x^3)); log2e folded in
__device__ __forceinline__ float fast_gelu(float x) {
    float x2 = x * x;
    float s  = __fmaf_rn(0.10294325f, x2, 2.3022083f);   // coeffs * log2(e)
    float zs = x * s;
    float e  = __builtin_amdgcn_exp2f(zs);               // v_exp_f32: 2^x
    float r  = __builtin_amdgcn_rcpf(e + 1.0f);
    return __fmaf_rn(-x, r, x);   // x*sigmoid(1.5958(x+0.0447x^3))
}

// ---- kernel 1: fold weights (UT transposed + packed COEF) -------------------
__global__ __launch_bounds__(256) void prep_kernel(
    const float* __restrict__ Wp, const float* __restrict__ bp,
    const float* __restrict__ Wi, const float* __restrict__ bi,
    const float* __restrict__ Wo, const float* __restrict__ bo,
    const float* __restrict__ We1, const float* __restrict__ be1,
    const float* __restrict__ We2, float* ws)
{
    int t = blockIdx.x * 256 + threadIdx.x;   // 0..16383
    int sel = t >> 13;                        // 0: Wi->UINT, 1: Wo->UOUTT
    int r = t & 8191;
    int g = r >> 6, dq = r & 63;
    const float* W = sel ? Wo : Wi;
    const float* wrow = We1 + g * FI;
    float4 acc = make_float4(0.f, 0.f, 0.f, 0.f);
    for (int f = 0; f < FI; ++f) {
        float w = wrow[f];
        float4 v = *(const float4*)(W + f * FD + dq * 4);
        acc.x = __fmaf_rn(w, v.x, acc.x);
        acc.y = __fmaf_rn(w, v.y, acc.y);
        acc.z = __fmaf_rn(w, v.z, acc.z);
        acc.w = __fmaf_rn(w, v.w, acc.w);
    }
    int base = (sel ? OFF_UOUTT : OFF_UINT) + (dq * 4) * FI + g;
    ws[base]           = acc.x;
    ws[base + FI]      = acc.y;
    ws[base + 2 * FI]  = acc.z;
    ws[base + 3 * FI]  = acc.w;

    if (blockIdx.x == 0 && t < FI) {
        const float* wr = We1 + t * FI;
        float a0 = 0.f, a1 = 0.f, abi = 0.f, abo = 0.f;
        for (int f = 0; f < FI; ++f) {
            float w = wr[f];
            a0  = __fmaf_rn(w, Wp[f * 2 + 0], a0);
            a1  = __fmaf_rn(w, Wp[f * 2 + 1], a1);
            abi = __fmaf_rn(w, bi[f] + bp[f], abi);
            abo = __fmaf_rn(w, bo[f], abo);
        }
        int gq = t >> 2, k = t & 3;
        ws[OFF_COEF + gq * 16 + k]     = a0;
        ws[OFF_COEF + gq * 16 + 4 + k] = a1;
        ws[OFF_COEF + gq * 16 + 8 + k] = We2[t];
        ws[OFF_BIN  + t] = abi + be1[t];
        ws[OFF_BOUT + t] = abo;
    }
}

// ---- kernel 2: per-node projections A_in', D (coalesced UT reads) -----------
__global__ __launch_bounds__(256) void node_proj_kernel(
    const float* __restrict__ x, float* ws)
{
    __shared__ __align__(16) float xs[4][FD];
    int nb = blockIdx.x * 4;                       // 512 blocks * 4 nodes
    ((float4*)xs)[threadIdx.x] = ((const float4*)(x + nb * FD))[threadIdx.x];
    __syncthreads();
    int t = threadIdx.x;
    int g = t & 127;
    bool isIn = (t < 128);
    const float* UT = ws + (isIn ? OFF_UINT : OFF_UOUTT);
    float bias = ws[(isIn ? OFF_BIN : OFF_BOUT) + g];
    float acc[4] = {0.f, 0.f, 0.f, 0.f};
    for (int d = 0; d < FD; d += 4) {
        #pragma unroll
        for (int k = 0; k < 4; ++k) {
            float u = UT[(d + k) * FI + g];
            #pragma unroll
            for (int n = 0; n < 4; ++n)
                acc[n] = __fmaf_rn(u, xs[n][d + k], acc[n]);
        }
    }
    #pragma unroll
    for (int n = 0; n < 4; ++n) {
        float val = acc[n] + bias;
        ws[(isIn ? OFF_AIN : OFF_D) + (nb + n) * FI + g] = isIn ? val : -val;
    }
}

// ---- kernel 3: fused edge MLP + supress + partial max over i ----------------
#define I_PER_BLOCK 16
#define I_PER_WAVE  4

__global__ __launch_bounds__(256) void edge_kernel(
    const float* __restrict__ pos, const float* __restrict__ sup,
    const float* __restrict__ Ain, const float* __restrict__ Dmat,
    const float* __restrict__ coef, const float* __restrict__ be2p,
    float* __restrict__ part)
{
    __shared__ __align__(16) float sD[64 * 130];   // only LDS array -> 4 blocks/CU

    int bid = blockIdx.x;            // 1024 = 4b * 8jt * 32ig
    int b   = bid >> 8;
    int jt  = (bid >> 5) & 7;
    int ig  = bid & 31;
    int tid = threadIdx.x;
    int w = tid >> 6, lane = tid & 63;
    int j = jt * 64 + lane;

    // stage D tile (float4 loads, padded rows)
    const float4* Dg4 = (const float4*)(Dmat + (b * NN + jt * 64) * FI);
    for (int s = tid; s < 64 * FI / 4; s += 256) {
        float4 v = Dg4[s];
        int r = s >> 5, c = (s & 31) * 4;
        float* p = &sD[r * 130 + c];
        p[0] = v.x; p[1] = v.y; p[2] = v.z; p[3] = v.w;
    }
    __syncthreads();

    int ibu = __builtin_amdgcn_readfirstlane(ig * I_PER_BLOCK + w * I_PER_WAVE);
    const float* Ab = Ain + (b * NN + ibu) * FI;   // wave-uniform base

    const float2* pos2 = (const float2*)pos;
    float p0[I_PER_WAVE], p1[I_PER_WAVE], su[I_PER_WAVE];
    #pragma unroll
    for (int ii = 0; ii < I_PER_WAVE; ++ii) {
        size_t eoff = (size_t)(b * NN + ibu + ii) * NN + j;
        float2 pp = pos2[eoff];
        p0[ii] = pp.x; p1[ii] = pp.y;
        su[ii] = sup[eoff];
    }

    float z[I_PER_WAVE] = {0.f, 0.f, 0.f, 0.f};
    const float2* sDp = (const float2*)sD + lane * 65;

    #pragma unroll 2
    for (int gq = 0; gq < FI / 4; ++gq) {
        float4 w0 = *(const float4*)(coef + gq * 16);
        float4 w1 = *(const float4*)(coef + gq * 16 + 4);
        float4 vv = *(const float4*)(coef + gq * 16 + 8);
        float2 d01 = sDp[gq * 2];
        float2 d23 = sDp[gq * 2 + 1];
        #pragma unroll
        for (int ii = 0; ii < I_PER_WAVE; ++ii) {
            float4 a = *(const float4*)(Ab + ii * FI + gq * 4);
            float y0 = __fmaf_rn(w1.x, p1[ii], __fmaf_rn(w0.x, p0[ii], a.x + d01.x));
            float y1 = __fmaf_rn(w1.y, p1[ii], __fmaf_rn(w0.y, p0[ii], a.y + d01.y));
            float y2 = __fmaf_rn(w1.z, p1[ii], __fmaf_rn(w0.z, p0[ii], a.z + d23.x));
            float y3 = __fmaf_rn(w1.w, p1[ii], __fmaf_rn(w0.w, p0[ii], a.w + d23.y));
            z[ii] = __fmaf_rn(vv.x, fast_gelu(y0), z[ii]);
            z[ii] = __fmaf_rn(vv.y, fast_gelu(y1), z[ii]);
            z[ii] = __fmaf_rn(vv.z, fast_gelu(y2), z[ii]);
            z[ii] = __fmaf_rn(vv.w, fast_gelu(y3), z[ii]);
        }
    }

    float be2 = *be2p;
    float m = -INFINITY;
    #pragma unroll
    for (int ii = 0; ii < I_PER_WAVE; ++ii)
        m = fmaxf(m, (z[ii] + be2) * su[ii]);
    part[((b * 128) + ig * 4 + w) * NN + j] = m;
}

// ---- kernel 4: reduce partials + node FFN -----------------------------------
__global__ __launch_bounds__(256) void final_kernel(
    const float* __restrict__ Wn1, const float* __restrict__ bn1,
    const float* __restrict__ Wn2, const float* __restrict__ bn2,
    const float* ws, float* __restrict__ out)
{
    __shared__ __align__(16) float red[16][17];
    __shared__ float nm[16];
    __shared__ __align__(16) float h1[16][FD];
    int nb = blockIdx.x * 16;                 // 128 blocks * 16 nodes
    int b  = nb >> 9;
    int j0 = nb & 511;
    int t = threadIdx.x;
    int k = t & 15, cc = t >> 4;
    const float* P = ws + OFF_PART + (size_t)b * 128 * NN;
    float m = -INFINITY;
    #pragma unroll
    for (int mm = 0; mm < 8; ++mm) {
        int c = cc + 16 * mm;
        m = fmaxf(m, P[c * NN + j0 + k]);
    }
    red[k][cc] = m;
    __syncthreads();
    if (t < 16) {
        float m2 = red[t][0];
        #pragma unroll
        for (int q = 1; q < 16; ++q) m2 = fmaxf(m2, red[t][q]);
        nm[t] = m2;
    }
    __syncthreads();
    {
        float wv = Wn1[t];        // Wn1 shape [256,1]
        float bv = bn1[t];
        #pragma unroll
        for (int kk = 0; kk < 16; ++kk)
            h1[kk][t] = fmaxf(0.f, __fmaf_rn(nm[kk], wv, bv));
    }
    __syncthreads();
    float acc[16];
    #pragma unroll
    for (int kk = 0; kk < 16; ++kk) acc[kk] = 0.f;
    const float4* w2 = (const float4*)(Wn2 + t * FD);
    for (int d4 = 0; d4 < FD / 4; ++d4) {
        float4 wv = w2[d4];
        #pragma unroll
        for (int kk = 0; kk < 16; ++kk) {
            float4 xv = ((const float4*)&h1[kk][0])[d4];
            acc[kk] = __fmaf_rn(wv.x, xv.x, acc[kk]);
            acc[kk] = __fmaf_rn(wv.y, xv.y, acc[kk]);
            acc[kk] = __fmaf_rn(wv.z, xv.z, acc[kk]);
            acc[kk] = __fmaf_rn(wv.w, xv.w, acc[kk]);
        }
    }
    float bb = bn2[t];
    #pragma unroll
    for (int kk = 0; kk < 16; ++kk)
        out[(size_t)(nb + kk) * FD + t] = fmaxf(0.f, acc[kk] + bb);
}

extern "C" void kernel_launch(void* const* d_in, const int* in_sizes, int n_in,
                              void* d_out, int out_size, void* d_ws, size_t ws_size,
                              hipStream_t stream) {
    (void)in_sizes; (void)n_in; (void)out_size; (void)ws_size;
    const float* node = (const float*)d_in[0];
    const float* sup  = (const float*)d_in[1];
    const float* pos  = (const float*)d_in[2];
    const float* Wp   = (const float*)d_in[3];
    const float* bp   = (const float*)d_in[4];
    const float* Wi   = (const float*)d_in[5];
    const float* bi   = (const float*)d_in[6];
    const float* Wo   = (const float*)d_in[7];
    const float* bo   = (const float*)d_in[8];
    const float* We1  = (const float*)d_in[9];
    const float* be1  = (const float*)d_in[10];
    const float* We2  = (const float*)d_in[11];
    const float* be2  = (const float*)d_in[12];
    const float* Wn1  = (const float*)d_in[13];
    const float* bn1  = (const float*)d_in[14];
    const float* Wn2  = (const float*)d_in[15];
    const float* bn2  = (const float*)d_in[16];
    float* ws  = (float*)d_ws;
    float* out = (float*)d_out;

    prep_kernel<<<64, 256, 0, stream>>>(Wp, bp, Wi, bi, Wo, bo, We1, be1, We2, ws);
    node_proj_kernel<<<512, 256, 0, stream>>>(node, ws);
    edge_kernel<<<1024, 256, 0, stream>>>(pos, sup,
                                          ws + OFF_AIN, ws + OFF_D,
                                          ws + OFF_COEF, be2,
                                          ws + OFF_PART);
    final_kernel<<<128, 256, 0, stream>>>(Wn1, bn1, Wn2, bn2, ws, out);
}

// Round 5
// 85.391 us; speedup vs baseline: 1.2793x; 1.2244x over previous
//
#include <hip/hip_runtime.h>
#include <hip/hip_bf16.h>

#define BB 4
#define NN 512
#define FD 256
#define FI 128

// workspace layout (float offsets)
#define OFF_AIN   0          // 2048*128  A_in' = We1@(Wi x + bi + bp) + be1
#define OFF_D     262144     // 2048*128  D = -We1@(Wo x + bo)
#define OFF_COEF  524288     // 32*16     per-gq packed {w0[4], w1[4], v[4], pad[4]}
#define OFF_PART  524800     // 4*32*512  per-(b, i-block) partial maxes
// total 590336 floats = 2.36 MB

// gelu(x) ~= x * sigmoid(1.5957691216*(x + 0.044715 x^3)); log2e folded in
__device__ __forceinline__ float fast_gelu(float x) {
    float x2 = x * x;
    float s  = __fmaf_rn(0.10294325f, x2, 2.3022083f);   // coeffs * log2(e)
    float zs = x * s;
    float e  = __builtin_amdgcn_exp2f(zs);               // v_exp_f32: 2^x
    float r  = __builtin_amdgcn_rcpf(e + 1.0f);
    return __fmaf_rn(-x, r, x);
}

// ---- kernel 1: fused node projections (h = W x + b, then A/D = We1 h) -------
__global__ __launch_bounds__(256) void node_fused_kernel(
    const float* __restrict__ x,
    const float* __restrict__ Wp,  const float* __restrict__ bp,
    const float* __restrict__ Wi,  const float* __restrict__ bi,
    const float* __restrict__ Wo,  const float* __restrict__ bo,
    const float* __restrict__ We1, const float* __restrict__ be1,
    const float* __restrict__ We2, float* ws)
{
    __shared__ __align__(16) float xs[8][FD];        // 8 KB
    __shared__ __align__(16) float hbuf[2][8][FI];   // 8 KB
    int t  = threadIdx.x;
    int nb = blockIdx.x * 8;                         // 256 blocks * 8 nodes

    // block 0 also produces the packed coef table (edge-kernel constants)
    if (blockIdx.x == 0 && t < FI) {
        const float* wr = We1 + t * FI;
        float a0 = 0.f, a1 = 0.f;
        for (int f = 0; f < FI; ++f) {
            float w = wr[f];
            a0 = __fmaf_rn(w, Wp[f * 2 + 0], a0);
            a1 = __fmaf_rn(w, Wp[f * 2 + 1], a1);
        }
        int gq = t >> 2, k = t & 3;
        ws[OFF_COEF + gq * 16 + k]     = a0;
        ws[OFF_COEF + gq * 16 + 4 + k] = a1;
        ws[OFF_COEF + gq * 16 + 8 + k] = We2[t];
    }

    // stage x rows
    ((float4*)xs)[t]       = ((const float4*)(x + nb * FD))[t];
    ((float4*)xs)[t + 256] = ((const float4*)(x + nb * FD))[t + 256];
    __syncthreads();

    // stage B: h[io][n][f] = W_io[f,:] . x[n,:] + bias
    int io = t >> 7, f = t & 127;
    const float* Wrow = (io ? Wo : Wi) + f * FD;
    float bias = io ? bo[f] : (bi[f] + bp[f]);
    float acc[8] = {0.f,0.f,0.f,0.f,0.f,0.f,0.f,0.f};
    for (int d4 = 0; d4 < FD / 4; ++d4) {
        float4 wv = ((const float4*)Wrow)[d4];
        #pragma unroll
        for (int n = 0; n < 8; ++n) {
            float4 xv = ((const float4*)&xs[n][0])[d4];
            acc[n] = __fmaf_rn(wv.x, xv.x, acc[n]);
            acc[n] = __fmaf_rn(wv.y, xv.y, acc[n]);
            acc[n] = __fmaf_rn(wv.z, xv.z, acc[n]);
            acc[n] = __fmaf_rn(wv.w, xv.w, acc[n]);
        }
    }
    #pragma unroll
    for (int n = 0; n < 8; ++n) hbuf[io][n][f] = acc[n] + bias;
    __syncthreads();

    // stage C: A_in[n][g] = We1[g,:] . h_in[n,:] + be1[g];  D[n][g] = -We1[g,:] . h_out[n,:]
    int g = f;
    const float* Erow = We1 + g * FI;
    float acc2[8] = {0.f,0.f,0.f,0.f,0.f,0.f,0.f,0.f};
    for (int f4 = 0; f4 < FI / 4; ++f4) {
        float4 ev = ((const float4*)Erow)[f4];
        #pragma unroll
        for (int n = 0; n < 8; ++n) {
            float4 hv = ((const float4*)&hbuf[io][n][0])[f4];
            acc2[n] = __fmaf_rn(ev.x, hv.x, acc2[n]);
            acc2[n] = __fmaf_rn(ev.y, hv.y, acc2[n]);
            acc2[n] = __fmaf_rn(ev.z, hv.z, acc2[n]);
            acc2[n] = __fmaf_rn(ev.w, hv.w, acc2[n]);
        }
    }
    if (io == 0) {
        float bg = be1[g];
        #pragma unroll
        for (int n = 0; n < 8; ++n)
            ws[OFF_AIN + (nb + n) * FI + g] = acc2[n] + bg;
    } else {
        #pragma unroll
        for (int n = 0; n < 8; ++n)
            ws[OFF_D + (nb + n) * FI + g] = -acc2[n];
    }
}

// ---- kernel 2: fused edge MLP + supress + block max over i ------------------
// 1024 blocks = 4b * 8jt * 32ig; 512 threads = 8 waves; 2 i-rows per wave
__global__ __launch_bounds__(512) void edge_kernel(
    const float* __restrict__ pos, const float* __restrict__ sup,
    const float* __restrict__ Ain, const float* __restrict__ Dmat,
    const float* __restrict__ coef, const float* __restrict__ be2p,
    float* __restrict__ part)
{
    __shared__ __align__(16) float sD[64 * 128];   // XOR-swizzled, 32 KB
    __shared__ __align__(16) float sA[16 * 128];   // 8 KB
    __shared__ __align__(16) float sC[512];        // 2 KB
    __shared__ float sP[8][64];                    // 2 KB  -> total 45056 B

    int bid = blockIdx.x;
    int b   = bid >> 8;
    int jt  = (bid >> 5) & 7;
    int ig  = bid & 31;
    int tid = threadIdx.x;
    int w = tid >> 6, lane = tid & 63;
    int j = jt * 64 + lane;

    // stage D tile with XOR swizzle: word = r*128 + (c ^ ((r&7)<<2))
    const float4* Dg4 = (const float4*)(Dmat + (b * NN + jt * 64) * FI);
    #pragma unroll
    for (int k = 0; k < 4; ++k) {
        int s = tid + k * 512;
        float4 v = Dg4[s];
        int r = s >> 5, c = (s & 31) * 4;
        *(float4*)(sD + r * 128 + (c ^ ((r & 7) << 2))) = v;
    }
    // stage A (16 rows) + coef
    ((float4*)sA)[tid & 511] = ((const float4*)(Ain + (b * NN + ig * 16) * FI))[tid];
    if (tid < 128) ((float4*)sC)[tid] = ((const float4*)coef)[tid];
    __syncthreads();

    int ibase = ig * 16 + w * 2;
    const float2* pos2 = (const float2*)pos;
    float p0[2], p1[2], su[2];
    #pragma unroll
    for (int ii = 0; ii < 2; ++ii) {
        size_t eoff = (size_t)(b * NN + ibase + ii) * NN + j;
        float2 pp = pos2[eoff];
        p0[ii] = pp.x; p1[ii] = pp.y;
        su[ii] = sup[eoff];
    }

    float z[2] = {0.f, 0.f};
    int dbase = lane * 128;
    int abase = w * 2 * FI;
    int dswz  = (lane & 7) << 2;

    #pragma unroll 4
    for (int gq = 0; gq < FI / 4; ++gq) {
        float4 d  = *(const float4*)(sD + dbase + ((gq * 4) ^ dswz));
        float4 w0 = *(const float4*)(sC + gq * 16);
        float4 w1 = *(const float4*)(sC + gq * 16 + 4);
        float4 vv = *(const float4*)(sC + gq * 16 + 8);
        #pragma unroll
        for (int ii = 0; ii < 2; ++ii) {
            float4 a = *(const float4*)(sA + abase + ii * FI + gq * 4);
            float y0 = __fmaf_rn(w1.x, p1[ii], __fmaf_rn(w0.x, p0[ii], a.x + d.x));
            float y1 = __fmaf_rn(w1.y, p1[ii], __fmaf_rn(w0.y, p0[ii], a.y + d.y));
            float y2 = __fmaf_rn(w1.z, p1[ii], __fmaf_rn(w0.z, p0[ii], a.z + d.z));
            float y3 = __fmaf_rn(w1.w, p1[ii], __fmaf_rn(w0.w, p0[ii], a.w + d.w));
            z[ii] = __fmaf_rn(vv.x, fast_gelu(y0), z[ii]);
            z[ii] = __fmaf_rn(vv.y, fast_gelu(y1), z[ii]);
            z[ii] = __fmaf_rn(vv.z, fast_gelu(y2), z[ii]);
            z[ii] = __fmaf_rn(vv.w, fast_gelu(y3), z[ii]);
        }
    }

    float be2 = *be2p;
    float m = fmaxf((z[0] + be2) * su[0], (z[1] + be2) * su[1]);
    sP[w][lane] = m;
    __syncthreads();
    if (tid < 64) {
        float mm = sP[0][tid];
        #pragma unroll
        for (int q = 1; q < 8; ++q) mm = fmaxf(mm, sP[q][tid]);
        part[(b * 32 + ig) * NN + jt * 64 + tid] = mm;
    }
}

// ---- kernel 3: reduce partials + node FFN -----------------------------------
__global__ __launch_bounds__(256) void final_kernel(
    const float* __restrict__ Wn1, const float* __restrict__ bn1,
    const float* __restrict__ Wn2, const float* __restrict__ bn2,
    const float* ws, float* __restrict__ out)
{
    __shared__ float red[8][33];
    __shared__ float nm[8];
    __shared__ __align__(16) float h1[8][FD];
    int nb = blockIdx.x * 8;                  // 256 blocks * 8 nodes
    int b  = nb >> 9;
    int j0 = nb & 511;
    int t = threadIdx.x;
    int k = t & 7, cc = t >> 3;               // cc in 0..31
    const float* P = ws + OFF_PART + (size_t)b * 32 * NN;
    red[k][cc] = P[cc * NN + j0 + k];
    __syncthreads();
    if (t < 8) {
        float m2 = red[t][0];
        #pragma unroll
        for (int q = 1; q < 32; ++q) m2 = fmaxf(m2, red[t][q]);
        nm[t] = m2;
    }
    __syncthreads();
    {
        float wv = Wn1[t];        // Wn1 shape [256,1]
        float bv = bn1[t];
        #pragma unroll
        for (int n = 0; n < 8; ++n)
            h1[n][t] = fmaxf(0.f, __fmaf_rn(nm[n], wv, bv));
    }
    __syncthreads();
    float acc[8] = {0.f,0.f,0.f,0.f,0.f,0.f,0.f,0.f};
    const float4* w2 = (const float4*)(Wn2 + t * FD);
    for (int d4 = 0; d4 < FD / 4; ++d4) {
        float4 wv = w2[d4];
        #pragma unroll
        for (int n = 0; n < 8; ++n) {
            float4 xv = ((const float4*)&h1[n][0])[d4];
            acc[n] = __fmaf_rn(wv.x, xv.x, acc[n]);
            acc[n] = __fmaf_rn(wv.y, xv.y, acc[n]);
            acc[n] = __fmaf_rn(wv.z, xv.z, acc[n]);
            acc[n] = __fmaf_rn(wv.w, xv.w, acc[n]);
        }
    }
    float bb = bn2[t];
    #pragma unroll
    for (int n = 0; n < 8; ++n)
        out[(size_t)(nb + n) * FD + t] = fmaxf(0.f, acc[n] + bb);
}

extern "C" void kernel_launch(void* const* d_in, const int* in_sizes, int n_in,
                              void* d_out, int out_size, void* d_ws, size_t ws_size,
                              hipStream_t stream) {
    (void)in_sizes; (void)n_in; (void)out_size; (void)ws_size;
    const float* node = (const float*)d_in[0];
    const float* sup  = (const float*)d_in[1];
    const float* pos  = (const float*)d_in[2];
    const float* Wp   = (const float*)d_in[3];
    const float* bp   = (const float*)d_in[4];
    const float* Wi   = (const float*)d_in[5];
    const float* bi   = (const float*)d_in[6];
    const float* Wo   = (const float*)d_in[7];
    const float* bo   = (const float*)d_in[8];
    const float* We1  = (const float*)d_in[9];
    const float* be1  = (const float*)d_in[10];
    const float* We2  = (const float*)d_in[11];
    const float* be2  = (const float*)d_in[12];
    const float* Wn1  = (const float*)d_in[13];
    const float* bn1  = (const float*)d_in[14];
    const float* Wn2  = (const float*)d_in[15];
    const float* bn2  = (const float*)d_in[16];
    float* ws  = (float*)d_ws;
    float* out = (float*)d_out;

    node_fused_kernel<<<256, 256, 0, stream>>>(node, Wp, bp, Wi, bi, Wo, bo,
                                               We1, be1, We2, ws);
    edge_kernel<<<1024, 512, 0, stream>>>(pos, sup,
                                          ws + OFF_AIN, ws + OFF_D,
                                          ws + OFF_COEF, be2,
                                          ws + OFF_PART);
    final_kernel<<<256, 256, 0, stream>>>(Wn1, bn1, Wn2, bn2, ws, out);
}